// Round 1
// baseline (258.860 us; speedup 1.0000x reference)
//
#include <hip/hip_runtime.h>
#include <hip/hip_bf16.h>

typedef __attribute__((ext_vector_type(8))) short short8;
typedef __attribute__((ext_vector_type(4))) float f32x4;

#define WS_WT_BYTES   18874368u   // 9*1024*1024 bf16
#define WS_B0_OFFSET  18874368u

// ---------------- Phase 0a: W[d][i][o] fp32 -> Wt[d][o][i] bf16 ----------------
__global__ void wt_kernel(const float* __restrict__ W, short* __restrict__ Wt) {
    __shared__ float t[64 * 65];
    int bid = blockIdx.x;
    int d   = bid >> 8;        // 256 tiles per d
    int rem = bid & 255;
    int i0  = (rem >> 4) << 6;
    int o0  = (rem & 15) << 6;
    const float* src = W + (size_t)d * 1048576;
    short* dst = Wt + (size_t)d * 1048576;
    int c  = threadIdx.x & 63;
    int rb = threadIdx.x >> 6;   // 0..3
#pragma unroll
    for (int k = 0; k < 16; k++) {
        int il = rb * 16 + k;
        t[il * 65 + c] = src[(size_t)(i0 + il) * 1024 + o0 + c];
    }
    __syncthreads();
#pragma unroll
    for (int k = 0; k < 16; k++) {
        int ol = rb * 16 + k;
        float v = t[c * 65 + ol];                       // = W[i0+c][o0+ol]
        dst[(size_t)(o0 + ol) * 1024 + i0 + c] =
            (short)__bfloat16_as_ushort(__float2bfloat16(v));
    }
}

// ---------------- Phase 0b: b0[o] = sum_i W[0][i][o] ----------------
__global__ void colsum_kernel(const float* __restrict__ W, float* __restrict__ b0) {
    int o = blockIdx.x * 256 + threadIdx.x;
    float s = 0.f;
#pragma unroll 8
    for (int i = 0; i < 1024; i++) s += W[(size_t)i * 1024 + o];
    b0[o] = s;
}

__device__ __forceinline__ short8 cvt8(const float* t) {
    short8 r;
#pragma unroll
    for (int j = 0; j < 8; j++)
        r[j] = (short)__bfloat16_as_ushort(__float2bfloat16(t[j]));
    return r;
}

// ---------------- Phase 1: fused tanh + Chebyshev + GEMM ----------------
// Block 256 thr = 4 waves (2x2 of 64x64). Tile 128x128, BK=32. K-order: i outer, d inner.
extern "C" __global__ void __launch_bounds__(256, 2)
cheby_gemm(const float* __restrict__ x, const short* __restrict__ Wt,
           const float* __restrict__ b0,
           const float* __restrict__ scp, const float* __restrict__ bip,
           float* __restrict__ out) {
    __shared__ __align__(16) float xt_lds[128 * 36];      // padded stride 36
    __shared__ __align__(16) short b_lds[2][4096];        // [buf][col(128)][k(32)] swizzled

    const int tid  = threadIdx.x;
    const int lane = tid & 63;
    const int wid  = tid >> 6;
    const int wr   = wid >> 1, wc = wid & 1;
    const int tn = blockIdx.x & 7, tm = blockIdx.x >> 3;  // same-tn blocks -> same XCD (bid%8)
    const int m0 = tm << 7, n0 = tn << 7;
    const float sc = scp[0], bi = bip[0];

    f32x4 acc[4][4];
#pragma unroll
    for (int n = 0; n < 4; n++) {
        float v = b0[n0 + wc * 64 + n * 16 + (lane & 15)];   // degree-0 contribution
#pragma unroll
        for (int m = 0; m < 4; m++) {
            f32x4 a = {v, v, v, v};
            acc[m][n] = a;
        }
    }

    int i0 = 0;

    auto stageB = [&](int d, int buf) {
        const short* wb = Wt + ((size_t)d << 20) + ((size_t)n0 << 10) + i0;
#pragma unroll
        for (int r = 0; r < 2; r++) {
            int t   = (r << 8) + tid;
            int col = t >> 2;
            int gk  = ((t & 3) ^ (col & 3)) << 3;            // inverse-swizzled source k
            const short* g = wb + ((size_t)col << 10) + gk;
            char* l = (char*)&b_lds[0][0] + buf * 8192 + ((r << 8) + (tid & ~63)) * 16;
            __builtin_amdgcn_global_load_lds(
                (const __attribute__((address_space(1))) void*)g,
                (__attribute__((address_space(3))) void*)l, 16, 0, 0);
        }
    };

    auto stage_xt = [&]() {
        const int w = tid >> 6, l = tid & 63;
        const int rbase = l >> 3;
        const int cb = (l & 7) * 4;
        f32x4 v[4];
#pragma unroll
        for (int q = 0; q < 4; q++) {
            int row = (w * 4 + q) * 8 + rbase;
            v[q] = *(const f32x4*)(x + (size_t)(m0 + row) * 1024 + i0 + cb);
        }
#pragma unroll
        for (int q = 0; q < 4; q++) {
            f32x4 tv;
#pragma unroll
            for (int e = 0; e < 4; e++) tv[e] = tanhf(fmaf(v[q][e], sc, bi));
            int row = (w * 4 + q) * 8 + rbase;
            *(f32x4*)(&xt_lds[row * 36 + cb]) = tv;
        }
    };

    auto ldb = [&](int rbuf, int n) -> short8 {
        int col = wc * 64 + n * 16 + (lane & 15);
        int g   = lane >> 4;
        int off = col * 64 + (((g ^ (col & 3))) << 4);        // XOR swizzle, keeps 16B align
        return *(const short8*)((const char*)&b_lds[0][0] + rbuf * 8192 + off);
    };

    auto step = [&](short8* af, int rbuf, int dnext) {
        if (dnext >= 0) stageB(dnext, rbuf ^ 1);
        short8 bf[4];
#pragma unroll
        for (int n = 0; n < 4; n++) bf[n] = ldb(rbuf, n);
#pragma unroll
        for (int m = 0; m < 4; m++)
#pragma unroll
            for (int n = 0; n < 4; n++)
                acc[m][n] = __builtin_amdgcn_mfma_f32_16x16x32_bf16(af[m], bf[n], acc[m][n], 0, 0, 0);
        __syncthreads();
    };

    for (int ic = 0; ic < 32; ic++) {
        i0 = ic << 5;
        stageB(1, 0);          // first needed degree into buf0
        stage_xt();
        __syncthreads();

        // load xt fragments -> fp32 recurrence state in registers
        float x2[4][8], tA[4][8], tB[4][8];
#pragma unroll
        for (int m = 0; m < 4; m++) {
            int row = wr * 64 + m * 16 + (lane & 15);
            const float* xp = &xt_lds[row * 36 + (lane >> 4) * 8];
            f32x4 lo = *(const f32x4*)xp;
            f32x4 hi = *(const f32x4*)(xp + 4);
#pragma unroll
            for (int j = 0; j < 4; j++) { tA[m][j] = lo[j]; tA[m][j + 4] = hi[j]; }
#pragma unroll
            for (int j = 0; j < 8; j++) x2[m][j] = tA[m][j] + tA[m][j];
        }

        short8 af[4];
        // d=1 : T1 = xt
#pragma unroll
        for (int m = 0; m < 4; m++) af[m] = cvt8(tA[m]);
        step(af, 0, 2);
        // d=2 : T2 = 2x*T1 - 1
#pragma unroll
        for (int m = 0; m < 4; m++) {
#pragma unroll
            for (int j = 0; j < 8; j++) tB[m][j] = fmaf(x2[m][j], tA[m][j], -1.0f);
            af[m] = cvt8(tB[m]);
        }
        step(af, 1, 3);

#define RECUR_STEP(DST, SRC, RBUF, DNEXT)                                      \
        {                                                                      \
_Pragma("unroll")                                                              \
            for (int m = 0; m < 4; m++) {                                      \
_Pragma("unroll")                                                              \
                for (int j = 0; j < 8; j++)                                    \
                    DST[m][j] = fmaf(x2[m][j], SRC[m][j], -DST[m][j]);         \
                af[m] = cvt8(DST[m]);                                          \
            }                                                                  \
            step(af, RBUF, DNEXT);                                             \
        }

        RECUR_STEP(tA, tB, 0, 4)   // d=3
        RECUR_STEP(tB, tA, 1, 5)   // d=4
        RECUR_STEP(tA, tB, 0, 6)   // d=5
        RECUR_STEP(tB, tA, 1, 7)   // d=6
        RECUR_STEP(tA, tB, 0, 8)   // d=7
        RECUR_STEP(tB, tA, 1, -1)  // d=8
#undef RECUR_STEP
    }

    // epilogue: C/D layout col=lane&15, row=(lane>>4)*4+reg
#pragma unroll
    for (int m = 0; m < 4; m++) {
        int rb = m0 + wr * 64 + m * 16 + ((lane >> 4) << 2);
#pragma unroll
        for (int n = 0; n < 4; n++) {
            int cc = n0 + wc * 64 + n * 16 + (lane & 15);
#pragma unroll
            for (int r = 0; r < 4; r++)
                out[(size_t)(rb + r) * 1024 + cc] = acc[m][n][r];
        }
    }
}

extern "C" void kernel_launch(void* const* d_in, const int* in_sizes, int n_in,
                              void* d_out, int out_size, void* d_ws, size_t ws_size,
                              hipStream_t stream) {
    const float* x  = (const float*)d_in[0];
    const float* W  = (const float*)d_in[1];
    const float* sc = (const float*)d_in[2];
    const float* bi = (const float*)d_in[3];
    float* out = (float*)d_out;

    short* Wt = (short*)d_ws;                                  // 18.9 MB bf16, [d][o][i]
    float* b0 = (float*)((char*)d_ws + WS_B0_OFFSET);          // 4 KB

    hipLaunchKernelGGL(wt_kernel, dim3(9 * 256), dim3(256), 0, stream, W, Wt);
    hipLaunchKernelGGL(colsum_kernel, dim3(4), dim3(256), 0, stream, W, b0);
    hipLaunchKernelGGL(cheby_gemm, dim3(512), dim3(256), 0, stream, x, Wt, b0, sc, bi, out);
}

// Round 2
// 193.052 us; speedup vs baseline: 1.3409x; 1.3409x over previous
//
#include <hip/hip_runtime.h>
#include <hip/hip_bf16.h>

typedef __attribute__((ext_vector_type(8))) short short8;
typedef __attribute__((ext_vector_type(4))) float f32x4;

#define WS_B0_OFFSET  18874368u   // b0 after Wt (9*1024*1024 bf16)

// ---------------- Phase 0a: W[d][i][o] fp32 -> Wt[d][o][i] bf16 ----------------
__global__ void wt_kernel(const float* __restrict__ W, short* __restrict__ Wt) {
    __shared__ float t[64 * 65];
    int bid = blockIdx.x;
    int d   = bid >> 8;
    int rem = bid & 255;
    int i0  = (rem >> 4) << 6;
    int o0  = (rem & 15) << 6;
    const float* src = W + (size_t)d * 1048576;
    short* dst = Wt + (size_t)d * 1048576;
    int c  = threadIdx.x & 63;
    int rb = threadIdx.x >> 6;
#pragma unroll
    for (int k = 0; k < 16; k++) {
        int il = rb * 16 + k;
        t[il * 65 + c] = src[(size_t)(i0 + il) * 1024 + o0 + c];
    }
    __syncthreads();
#pragma unroll
    for (int k = 0; k < 16; k++) {
        int ol = rb * 16 + k;
        float v = t[c * 65 + ol];
        dst[(size_t)(o0 + ol) * 1024 + i0 + c] =
            (short)__bfloat16_as_ushort(__float2bfloat16(v));
    }
}

// ---------------- Phase 0b: b0[o] = sum_i W[0][i][o], two-stage ----------------
__global__ void colsum1(const float* __restrict__ W, float* __restrict__ part) {
    int s = blockIdx.x >> 2;                       // 32 slices of 32 rows
    int o = (blockIdx.x & 3) * 256 + threadIdx.x;
    const float* p = W + (size_t)s * 32 * 1024 + o;
    float acc = 0.f;
#pragma unroll
    for (int i = 0; i < 32; i++) acc += p[(size_t)i * 1024];
    part[s * 1024 + o] = acc;
}
__global__ void colsum2(const float* __restrict__ part, float* __restrict__ b0) {
    int o = blockIdx.x * 256 + threadIdx.x;
    float acc = 0.f;
#pragma unroll
    for (int s = 0; s < 32; s++) acc += part[s * 1024 + o];
    b0[o] = acc;
}

__device__ __forceinline__ float fast_tanh(float t) {
    float e = __expf(t + t);
    return 1.0f - 2.0f * __builtin_amdgcn_rcpf(e + 1.0f);
}

__device__ __forceinline__ short8 cvt8(const float* t) {
    short8 r;
#pragma unroll
    for (int j = 0; j < 8; j++)
        r[j] = (short)__bfloat16_as_ushort(__float2bfloat16(t[j]));
    return r;
}

// ---------------- Phase 1: fused tanh + Chebyshev + GEMM ----------------
// 256 thr = 4 waves (2x2 of 64x64). Tile 128x128, BK=32, K-order: i outer, d inner.
// B triple-buffered in LDS (stage d+2 during step d), counted vmcnt, raw barriers.
extern "C" __global__ void __launch_bounds__(256, 2)
cheby_gemm(const float* __restrict__ x, const short* __restrict__ Wt,
           const float* __restrict__ b0v, const float* __restrict__ scp,
           const float* __restrict__ bip, float* __restrict__ out) {
    __shared__ __align__(16) short b_lds[3][4096];   // 3 x (128 col x 32 k), swizzled

    const int tid = threadIdx.x, lane = tid & 63, wid = tid >> 6;
    const int wr = wid >> 1, wc = wid & 1;
    const int tn = blockIdx.x & 7, tm = blockIdx.x >> 3;  // bid%8 -> XCD-local B panel
    const int m0 = tm << 7, n0 = tn << 7;
    const float sc = scp[0], bi = bip[0];

    // B-read LDS byte offsets per n (swizzle: slot = col*4 + (g ^ ((col>>1)&3)))
    int boff[4];
#pragma unroll
    for (int n = 0; n < 4; n++) {
        int col = wc * 64 + n * 16 + (lane & 15);
        int g   = lane >> 4;
        boff[n] = (col * 4 + (g ^ ((col >> 1) & 3))) * 16;
    }
    // staging constants: slot t holds chunk ((t&3)^swz(col)) of col=t>>2
    int goff[2], ldsoff[2];
#pragma unroll
    for (int r = 0; r < 2; r++) {
        int t   = (r << 8) + tid;
        int col = t >> 2;
        int gk  = ((t & 3) ^ ((col >> 1) & 3)) << 3;
        goff[r]   = (col << 10) + gk;
        ldsoff[r] = ((r << 8) + (tid & ~63)) << 4;
    }

    auto stageB = [&](int dd, int icc, int bf) {
        const short* wb = Wt + ((size_t)dd << 20) + ((size_t)n0 << 10) + (icc << 5);
#pragma unroll
        for (int r = 0; r < 2; r++)
            __builtin_amdgcn_global_load_lds(
                (const __attribute__((address_space(1))) void*)(wb + goff[r]),
                (__attribute__((address_space(3))) void*)((char*)&b_lds[0][0] + bf * 8192 + ldsoff[r]),
                16, 0, 0);
    };

    const float* xbase = x + (size_t)(m0 + wr * 64 + (lane & 15)) * 1024 + ((lane >> 4) << 3);
    f32x4 xv[4][2];
    auto loadx = [&](int icc) {
#pragma unroll
        for (int m = 0; m < 4; m++) {
            const float* xp = xbase + (size_t)(m << 4) * 1024 + (icc << 5);
            xv[m][0] = *(const f32x4*)xp;
            xv[m][1] = *(const f32x4*)(xp + 4);
        }
    };

    f32x4 acc[4][4];
#pragma unroll
    for (int n = 0; n < 4; n++) {
        float v = b0v[n0 + wc * 64 + n * 16 + (lane & 15)];   // degree-0 folded in
#pragma unroll
        for (int m = 0; m < 4; m++) acc[m][n] = (f32x4){v, v, v, v};
    }

    auto domfma = [&](short8* af, int bf) {
        short8 bfr[4];
#pragma unroll
        for (int n = 0; n < 4; n++)
            bfr[n] = *(const short8*)((const char*)&b_lds[0][0] + bf * 8192 + boff[n]);
        __builtin_amdgcn_s_setprio(1);
#pragma unroll
        for (int m = 0; m < 4; m++)
#pragma unroll
            for (int n = 0; n < 4; n++)
                acc[m][n] = __builtin_amdgcn_mfma_f32_16x16x32_bf16(af[m], bfr[n], acc[m][n], 0, 0, 0);
        __builtin_amdgcn_s_setprio(0);
    };

    // ---- prologue: d=1->buf0, d=2->buf1, x(ic0) ----
    stageB(1, 0, 0);
    stageB(2, 0, 1);
    loadx(0);
    __builtin_amdgcn_sched_barrier(0);
    asm volatile("s_waitcnt vmcnt(10)" ::: "memory");
    __builtin_amdgcn_s_barrier();

    int rb = 0;
    float x2[4][8], tA[4][8], tB[4][8];
    short8 af[4];

    // vmcnt plan per step end: {2,10,10,2,2,2,2,2}  (x8 issued at step1 after stage)
#define STEP_END(VM)                                             \
    __builtin_amdgcn_sched_barrier(0);                           \
    asm volatile("s_waitcnt vmcnt(" #VM ")" ::: "memory");       \
    __builtin_amdgcn_s_barrier();                                \
    rb = rb + 1; if (rb >= 3) rb -= 3;

#define NEXTBUF int s2 = rb + 2; if (s2 >= 3) s2 -= 3;

    for (int ic = 0; ic < 32; ++ic) {
        const int icn = ic + 1 < 32 ? ic + 1 : 31;

        { // step 0: d=1  (tanh from prefetched xv)
            NEXTBUF; stageB(3, ic, s2);
#pragma unroll
            for (int m = 0; m < 4; m++) {
#pragma unroll
                for (int e = 0; e < 4; e++) {
                    tA[m][e]     = fast_tanh(fmaf(xv[m][0][e], sc, bi));
                    tA[m][e + 4] = fast_tanh(fmaf(xv[m][1][e], sc, bi));
                }
#pragma unroll
                for (int e = 0; e < 8; e++) x2[m][e] = tA[m][e] + tA[m][e];
                af[m] = cvt8(tA[m]);
            }
            domfma(af, rb);
            STEP_END(2)
        }
        { // step 1: d=2, prefetch x for next ic
            NEXTBUF; stageB(4, ic, s2);
            loadx(icn);
#pragma unroll
            for (int m = 0; m < 4; m++) {
#pragma unroll
                for (int e = 0; e < 8; e++) tB[m][e] = fmaf(x2[m][e], tA[m][e], -1.0f);
                af[m] = cvt8(tB[m]);
            }
            domfma(af, rb);
            STEP_END(10)
        }

#define RECUR_STEP(DST, SRC, DDSTAGE, ICSTAGE, VM)                            \
        {                                                                     \
            NEXTBUF; stageB(DDSTAGE, ICSTAGE, s2);                            \
_Pragma("unroll")                                                             \
            for (int m = 0; m < 4; m++) {                                     \
_Pragma("unroll")                                                             \
                for (int e = 0; e < 8; e++)                                   \
                    DST[m][e] = fmaf(x2[m][e], SRC[m][e], -DST[m][e]);        \
                af[m] = cvt8(DST[m]);                                         \
            }                                                                 \
            domfma(af, rb);                                                   \
            STEP_END(VM)                                                      \
        }

        RECUR_STEP(tA, tB, 5, ic, 10)   // step 2: d=3
        RECUR_STEP(tB, tA, 6, ic, 2)    // step 3: d=4
        RECUR_STEP(tA, tB, 7, ic, 2)    // step 4: d=5
        RECUR_STEP(tB, tA, 8, ic, 2)    // step 5: d=6
        RECUR_STEP(tA, tB, 1, icn, 2)   // step 6: d=7, stage next-ic d=1
        RECUR_STEP(tB, tA, 2, icn, 2)   // step 7: d=8, stage next-ic d=2
#undef RECUR_STEP
    }

    // keep the final (dead) x-prefetch alive so the vmcnt FIFO accounting holds (rule #17)
    {
        float keep = xv[0][0][0] + xv[1][0][0] + xv[2][0][0] + xv[3][0][0]
                   + xv[0][1][0] + xv[1][1][0] + xv[2][1][0] + xv[3][1][0];
        acc[0][0][0] = fmaf(keep, 1e-40f, acc[0][0][0]);
    }

    // epilogue: C/D layout col=lane&15, row=(lane>>4)*4+reg
#pragma unroll
    for (int m = 0; m < 4; m++) {
        int rbow = m0 + wr * 64 + m * 16 + ((lane >> 4) << 2);
#pragma unroll
        for (int n = 0; n < 4; n++) {
            int cc = n0 + wc * 64 + n * 16 + (lane & 15);
#pragma unroll
            for (int r = 0; r < 4; r++)
                out[(size_t)(rbow + r) * 1024 + cc] = acc[m][n][r];
        }
    }
#undef STEP_END
#undef NEXTBUF
}

extern "C" void kernel_launch(void* const* d_in, const int* in_sizes, int n_in,
                              void* d_out, int out_size, void* d_ws, size_t ws_size,
                              hipStream_t stream) {
    const float* x  = (const float*)d_in[0];
    const float* W  = (const float*)d_in[1];
    const float* sc = (const float*)d_in[2];
    const float* bi = (const float*)d_in[3];
    float* out = (float*)d_out;

    short* Wt = (short*)d_ws;
    float* b0 = (float*)((char*)d_ws + WS_B0_OFFSET);
    float* part = out;   // colsum partials staged in d_out (fully overwritten by gemm)

    hipLaunchKernelGGL(wt_kernel, dim3(9 * 256), dim3(256), 0, stream, W, Wt);
    hipLaunchKernelGGL(colsum1, dim3(128), dim3(256), 0, stream, W, part);
    hipLaunchKernelGGL(colsum2, dim3(4), dim3(256), 0, stream, part, b0);
    hipLaunchKernelGGL(cheby_gemm, dim3(512), dim3(256), 0, stream, x, Wt, b0, sc, bi, out);
}